// Round 1
// baseline (2875.602 us; speedup 1.0000x reference)
//
#include <hip/hip_runtime.h>
#include <cmath>

#define N_NODES_C 50000
#define N_EDGES_C 800000
#define HIDDEN_C  128
#define MSG_C     64
#define NPB       32   // nodes per block in node_kernel

__device__ __forceinline__ float sigmoidf_(float x) {
    return 1.0f / (1.0f + __expf(-x));
}
__device__ __forceinline__ float tanhf_(float x) {
    // tanh via exp(-2|x|): safe at large |x| (t -> 0 => r -> 1)
    float t = __expf(-2.0f * fabsf(x));
    float r = (1.0f - t) / (1.0f + t);
    return copysignf(r, x);
}

// ---------------- transpose weights: W[g][k] -> WT[k][g] ----------------
__global__ void transpose_w(const float* __restrict__ Wih,
                            const float* __restrict__ Whh,
                            float* __restrict__ WTih,
                            float* __restrict__ WThh) {
    int i = blockIdx.x * blockDim.x + threadIdx.x;
    if (i < 256 * 128) {
        int g = i >> 7, k = i & 127;
        WTih[k * 256 + g] = Wih[i];
    }
    if (i < 256 * 64) {
        int g = i >> 6, k = i & 63;
        WThh[k * 256 + g] = Whh[i];
    }
}

// ---------------- edge scatter: sum[dst] += feat[src], cnt[dst] += 1 ----
// 32 lanes per edge, float4 per lane (128 floats/row)
__global__ __launch_bounds__(256) void edge_scatter(
    const float4* __restrict__ feat4,
    const int* __restrict__ src,
    const int* __restrict__ dst,
    float* __restrict__ sum,
    float* __restrict__ cnt,
    int nE) {
    int gid  = blockIdx.x * blockDim.x + threadIdx.x;
    int edge = gid >> 5;
    int lane = gid & 31;
    if (edge >= nE) return;
    int s = src[edge];
    int d = dst[edge];
    float4 v = feat4[(long)s * 32 + lane];
    float* p = sum + (long)d * 128 + lane * 4;
    atomicAdd(p + 0, v.x);
    atomicAdd(p + 1, v.y);
    atomicAdd(p + 2, v.z);
    atomicAdd(p + 3, v.w);
    if (lane == 0) atomicAdd(cnt + d, 1.0f);
}

// ---------------- node kernel: rst + gates GEMM + LSTM epilogue --------
__global__ __launch_bounds__(256) void node_kernel(
    const float* __restrict__ feat,
    const float* __restrict__ sum0, const float* __restrict__ cnt0,
    const float* __restrict__ sum1, const float* __restrict__ cnt1,
    const float* __restrict__ WTih, const float* __restrict__ WThh,
    const float* __restrict__ b_ih, const float* __restrict__ b_hh,
    float* __restrict__ out) {
    __shared__ float feat_s[NPB][HIDDEN_C];
    __shared__ float rst_s[NPB][HIDDEN_C];

    int t  = threadIdx.x;
    int nb = blockIdx.x * NPB;

    // Phase A: load feat tile, compute rst tile (mean0/mean1 combine)
    for (int idx = t; idx < NPB * HIDDEN_C; idx += 256) {
        int n = idx >> 7, k = idx & 127;
        int gn = nb + n;
        float fv = 0.0f, rv = 0.0f;
        if (gn < N_NODES_C) {
            fv = feat[(long)gn * 128 + k];
            float c0 = cnt0[gn], c1 = cnt1[gn];
            float m0 = sum0[(long)gn * 128 + k] / fmaxf(c0, 1.0f);
            float m1 = sum1[(long)gn * 128 + k] / fmaxf(c1, 1.0f);
            float na = fmaxf((c0 > 0.0f ? 1.0f : 0.0f) + (c1 > 0.0f ? 1.0f : 0.0f), 1.0f);
            rv = (m0 + m1) / na;
        }
        feat_s[n][k] = fv;
        rst_s[n][k]  = rv;
    }
    __syncthreads();

    int lane = t & 63;   // = gate dim m
    int wv   = t >> 6;   // wave id 0..3; node_local = wv + 4*it

    float bias[4];
#pragma unroll
    for (int c = 0; c < 4; c++) bias[c] = b_ih[c * 64 + lane] + b_hh[c * 64 + lane];

    float acc[8][4];
#pragma unroll
    for (int it = 0; it < 8; it++)
#pragma unroll
        for (int c = 0; c < 4; c++) acc[it][c] = bias[c];

    // feat @ W_ih^T  (k = 0..127)
    for (int k = 0; k < 128; k++) {
        float w0 = WTih[k * 256 + 0 * 64 + lane];
        float w1 = WTih[k * 256 + 1 * 64 + lane];
        float w2 = WTih[k * 256 + 2 * 64 + lane];
        float w3 = WTih[k * 256 + 3 * 64 + lane];
#pragma unroll
        for (int it = 0; it < 8; it++) {
            float fv = feat_s[wv + 4 * it][k];
            acc[it][0] = fmaf(fv, w0, acc[it][0]);
            acc[it][1] = fmaf(fv, w1, acc[it][1]);
            acc[it][2] = fmaf(fv, w2, acc[it][2]);
            acc[it][3] = fmaf(fv, w3, acc[it][3]);
        }
    }
    // G_t @ W_hh^T  (k = 0..63, G = rst[:, :64])
    for (int k = 0; k < 64; k++) {
        float w0 = WThh[k * 256 + 0 * 64 + lane];
        float w1 = WThh[k * 256 + 1 * 64 + lane];
        float w2 = WThh[k * 256 + 2 * 64 + lane];
        float w3 = WThh[k * 256 + 3 * 64 + lane];
#pragma unroll
        for (int it = 0; it < 8; it++) {
            float gv = rst_s[wv + 4 * it][k];
            acc[it][0] = fmaf(gv, w0, acc[it][0]);
            acc[it][1] = fmaf(gv, w1, acc[it][1]);
            acc[it][2] = fmaf(gv, w2, acc[it][2]);
            acc[it][3] = fmaf(gv, w3, acc[it][3]);
        }
    }

    // Epilogue: LSTM cell
#pragma unroll
    for (int it = 0; it < 8; it++) {
        int n  = wv + 4 * it;
        int gn = nb + n;
        if (gn >= N_NODES_C) continue;
        float R  = rst_s[n][64 + lane];
        float iv = sigmoidf_(acc[it][0]);
        float fv = sigmoidf_(acc[it][1]);
        float gv = tanhf_(acc[it][2]);
        float ov = sigmoidf_(acc[it][3]);
        float c1 = fv * R + iv * gv;
        float h1 = ov * tanhf_(c1);
        out[(long)gn * 128 + lane]      = h1;
        out[(long)gn * 128 + 64 + lane] = c1;
    }
}

extern "C" void kernel_launch(void* const* d_in, const int* in_sizes, int n_in,
                              void* d_out, int out_size, void* d_ws, size_t ws_size,
                              hipStream_t stream) {
    const float* feat = (const float*)d_in[0];
    const int*   src0 = (const int*)d_in[1];
    const int*   dst0 = (const int*)d_in[2];
    const int*   src1 = (const int*)d_in[3];
    const int*   dst1 = (const int*)d_in[4];
    const float* W_ih = (const float*)d_in[5];
    const float* W_hh = (const float*)d_in[6];
    const float* b_ih = (const float*)d_in[7];
    const float* b_hh = (const float*)d_in[8];
    float* out = (float*)d_out;

    float* ws   = (float*)d_ws;
    float* sum0 = ws;                         // 6,400,000
    float* sum1 = sum0 + 6400000;             // 6,400,000
    float* cnt0 = sum1 + 6400000;             // 50,000
    float* cnt1 = cnt0 + 50000;               // 50,000
    float* WTih = cnt1 + 50000;               // 32,768
    float* WThh = WTih + 32768;               // 16,384

    // zero accumulators (sums + counts) every call — ws not re-poisoned
    hipMemsetAsync(d_ws, 0, (size_t)(2 * 6400000 + 2 * 50000) * sizeof(float), stream);

    transpose_w<<<128, 256, 0, stream>>>(W_ih, W_hh, WTih, WThh);

    int blocksE = (N_EDGES_C * 32 + 255) / 256;  // 100000
    edge_scatter<<<blocksE, 256, 0, stream>>>((const float4*)feat, src0, dst0, sum0, cnt0, N_EDGES_C);
    edge_scatter<<<blocksE, 256, 0, stream>>>((const float4*)feat, src1, dst1, sum1, cnt1, N_EDGES_C);

    int blocksN = (N_NODES_C + NPB - 1) / NPB;   // 1563
    node_kernel<<<blocksN, 256, 0, stream>>>(feat, sum0, cnt0, sum1, cnt1,
                                             WTih, WThh, b_ih, b_hh, out);
}

// Round 2
// 557.107 us; speedup vs baseline: 5.1617x; 5.1617x over previous
//
#include <hip/hip_runtime.h>
#include <cmath>

#define NN 50000
#define NE 800000
#define HIDDEN_C 128
#define NPB 32

__device__ __forceinline__ float sigmoidf_(float x) {
    return 1.0f / (1.0f + __expf(-x));
}
__device__ __forceinline__ float tanhf_(float x) {
    float t = __expf(-2.0f * fabsf(x));
    float r = (1.0f - t) / (1.0f + t);
    return copysignf(r, x);
}

// ---------------- transpose weights: W[g][k] -> WT[k][g] ----------------
__global__ void transpose_w(const float* __restrict__ Wih,
                            const float* __restrict__ Whh,
                            float* __restrict__ WTih,
                            float* __restrict__ WThh) {
    int i = blockIdx.x * blockDim.x + threadIdx.x;
    if (i < 256 * 128) {
        int g = i >> 7, k = i & 127;
        WTih[k * 256 + g] = Wih[i];
    }
    if (i < 256 * 64) {
        int g = i >> 6, k = i & 63;
        WThh[k * 256 + g] = Whh[i];
    }
}

// ---------------- CSR build ----------------
__global__ void hist_kernel(const int* __restrict__ dst0, const int* __restrict__ dst1,
                            int* __restrict__ deg0, int* __restrict__ deg1) {
    int e = blockIdx.x * blockDim.x + threadIdx.x;
    if (e < NE) {
        atomicAdd(&deg0[dst0[e]], 1);
        atomicAdd(&deg1[dst1[e]], 1);
    }
}

// one block per etype (grid = 2): 1024-thread single-block exclusive scan
__global__ __launch_bounds__(1024) void scan_kernel(const int* __restrict__ deg0, int* __restrict__ off0, int* __restrict__ cur0,
                                                    const int* __restrict__ deg1, int* __restrict__ off1, int* __restrict__ cur1) {
    const int* deg = blockIdx.x == 0 ? deg0 : deg1;
    int* off = blockIdx.x == 0 ? off0 : off1;
    int* cur = blockIdx.x == 0 ? cur0 : cur1;

    __shared__ int tot[1024];
    int tid = threadIdx.x;
    const int chunk = (NN + 1023) / 1024;  // 49
    int base = tid * chunk;
    int s = 0;
    for (int i = 0; i < chunk; i++) {
        int idx = base + i;
        if (idx < NN) s += deg[idx];
    }
    tot[tid] = s;
    __syncthreads();
    for (int d = 1; d < 1024; d <<= 1) {
        int v = (tid >= d) ? tot[tid - d] : 0;
        __syncthreads();
        tot[tid] += v;
        __syncthreads();
    }
    int run = (tid > 0) ? tot[tid - 1] : 0;
    for (int i = 0; i < chunk; i++) {
        int idx = base + i;
        if (idx < NN) {
            off[idx] = run;
            cur[idx] = run;
            run += deg[idx];
        }
    }
}

__global__ void scatter_kernel(const int* __restrict__ src0, const int* __restrict__ dst0,
                               const int* __restrict__ src1, const int* __restrict__ dst1,
                               int* __restrict__ cur0, int* __restrict__ cur1,
                               int* __restrict__ es0, int* __restrict__ es1) {
    int e = blockIdx.x * blockDim.x + threadIdx.x;
    if (e < NE) {
        int p0 = atomicAdd(&cur0[dst0[e]], 1);
        es0[p0] = src0[e];
        int p1 = atomicAdd(&cur1[dst1[e]], 1);
        es1[p1] = src1[e];
    }
}

// ---------------- gather: one wave per node, float2 per lane ----------------
__global__ __launch_bounds__(256) void gather_kernel(
    const float2* __restrict__ feat2,
    const int* __restrict__ es0, const int* __restrict__ off0, const int* __restrict__ deg0,
    const int* __restrict__ es1, const int* __restrict__ off1, const int* __restrict__ deg1,
    float2* __restrict__ rst2) {
    int wid  = (blockIdx.x * blockDim.x + threadIdx.x) >> 6;
    int lane = threadIdx.x & 63;
    if (wid >= NN) return;

    float ax0 = 0.f, ay0 = 0.f, ax1 = 0.f, ay1 = 0.f;
    int d0 = deg0[wid], o0 = off0[wid];
    for (int e = 0; e < d0; e++) {
        int s = es0[o0 + e];
        float2 v = feat2[(long)s * 64 + lane];
        ax0 += v.x; ay0 += v.y;
    }
    int d1 = deg1[wid], o1 = off1[wid];
    for (int e = 0; e < d1; e++) {
        int s = es1[o1 + e];
        float2 v = feat2[(long)s * 64 + lane];
        ax1 += v.x; ay1 += v.y;
    }
    float inv0 = 1.0f / fmaxf((float)d0, 1.0f);
    float inv1 = 1.0f / fmaxf((float)d1, 1.0f);
    float na = fmaxf((float)((d0 > 0) + (d1 > 0)), 1.0f);
    float2 r;
    r.x = (ax0 * inv0 + ax1 * inv1) / na;
    r.y = (ay0 * inv0 + ay1 * inv1) / na;
    rst2[(long)wid * 64 + lane] = r;
}

// ---------------- node kernel: gates GEMM + LSTM epilogue --------
__global__ __launch_bounds__(256) void node_kernel(
    const float* __restrict__ feat,
    const float* __restrict__ rst,
    const float* __restrict__ WTih, const float* __restrict__ WThh,
    const float* __restrict__ b_ih, const float* __restrict__ b_hh,
    float* __restrict__ out) {
    __shared__ float feat_s[NPB][HIDDEN_C];
    __shared__ float rst_s[NPB][HIDDEN_C];

    int t  = threadIdx.x;
    int nb = blockIdx.x * NPB;

    for (int idx = t; idx < NPB * HIDDEN_C; idx += 256) {
        int n = idx >> 7, k = idx & 127;
        int gn = nb + n;
        float fv = 0.0f, rv = 0.0f;
        if (gn < NN) {
            fv = feat[(long)gn * 128 + k];
            rv = rst[(long)gn * 128 + k];
        }
        feat_s[n][k] = fv;
        rst_s[n][k]  = rv;
    }
    __syncthreads();

    int lane = t & 63;
    int wv   = t >> 6;

    float bias[4];
#pragma unroll
    for (int c = 0; c < 4; c++) bias[c] = b_ih[c * 64 + lane] + b_hh[c * 64 + lane];

    float acc[8][4];
#pragma unroll
    for (int it = 0; it < 8; it++)
#pragma unroll
        for (int c = 0; c < 4; c++) acc[it][c] = bias[c];

    for (int k = 0; k < 128; k++) {
        float w0 = WTih[k * 256 + 0 * 64 + lane];
        float w1 = WTih[k * 256 + 1 * 64 + lane];
        float w2 = WTih[k * 256 + 2 * 64 + lane];
        float w3 = WTih[k * 256 + 3 * 64 + lane];
#pragma unroll
        for (int it = 0; it < 8; it++) {
            float fv = feat_s[wv + 4 * it][k];
            acc[it][0] = fmaf(fv, w0, acc[it][0]);
            acc[it][1] = fmaf(fv, w1, acc[it][1]);
            acc[it][2] = fmaf(fv, w2, acc[it][2]);
            acc[it][3] = fmaf(fv, w3, acc[it][3]);
        }
    }
    for (int k = 0; k < 64; k++) {
        float w0 = WThh[k * 256 + 0 * 64 + lane];
        float w1 = WThh[k * 256 + 1 * 64 + lane];
        float w2 = WThh[k * 256 + 2 * 64 + lane];
        float w3 = WThh[k * 256 + 3 * 64 + lane];
#pragma unroll
        for (int it = 0; it < 8; it++) {
            float gv = rst_s[wv + 4 * it][k];
            acc[it][0] = fmaf(gv, w0, acc[it][0]);
            acc[it][1] = fmaf(gv, w1, acc[it][1]);
            acc[it][2] = fmaf(gv, w2, acc[it][2]);
            acc[it][3] = fmaf(gv, w3, acc[it][3]);
        }
    }

#pragma unroll
    for (int it = 0; it < 8; it++) {
        int n  = wv + 4 * it;
        int gn = nb + n;
        if (gn >= NN) continue;
        float R  = rst_s[n][64 + lane];
        float iv = sigmoidf_(acc[it][0]);
        float fv = sigmoidf_(acc[it][1]);
        float gv = tanhf_(acc[it][2]);
        float ov = sigmoidf_(acc[it][3]);
        float c1 = fv * R + iv * gv;
        float h1 = ov * tanhf_(c1);
        out[(long)gn * 128 + lane]      = h1;
        out[(long)gn * 128 + 64 + lane] = c1;
    }
}

extern "C" void kernel_launch(void* const* d_in, const int* in_sizes, int n_in,
                              void* d_out, int out_size, void* d_ws, size_t ws_size,
                              hipStream_t stream) {
    const float* feat = (const float*)d_in[0];
    const int*   src0 = (const int*)d_in[1];
    const int*   dst0 = (const int*)d_in[2];
    const int*   src1 = (const int*)d_in[3];
    const int*   dst1 = (const int*)d_in[4];
    const float* W_ih = (const float*)d_in[5];
    const float* W_hh = (const float*)d_in[6];
    const float* b_ih = (const float*)d_in[7];
    const float* b_hh = (const float*)d_in[8];
    float* out = (float*)d_out;

    // workspace layout
    char* p = (char*)d_ws;
    int* deg0 = (int*)p;            p += NN * 4;     // zeroed
    int* deg1 = (int*)p;            p += NN * 4;     // zeroed
    int* off0 = (int*)p;            p += NN * 4;
    int* off1 = (int*)p;            p += NN * 4;
    int* cur0 = (int*)p;            p += NN * 4;
    int* cur1 = (int*)p;            p += NN * 4;
    int* es0  = (int*)p;            p += NE * 4;
    int* es1  = (int*)p;            p += NE * 4;
    float* rst  = (float*)p;        p += (size_t)NN * 128 * 4;
    float* WTih = (float*)p;        p += 256 * 128 * 4;
    float* WThh = (float*)p;        p += 256 * 64 * 4;

    // zero degree histograms only
    hipMemsetAsync(deg0, 0, 2 * NN * sizeof(int), stream);

    transpose_w<<<128, 256, 0, stream>>>(W_ih, W_hh, WTih, WThh);

    int blocksE = (NE + 255) / 256;  // 3125
    hist_kernel<<<blocksE, 256, 0, stream>>>(dst0, dst1, deg0, deg1);
    scan_kernel<<<2, 1024, 0, stream>>>(deg0, off0, cur0, deg1, off1, cur1);
    scatter_kernel<<<blocksE, 256, 0, stream>>>(src0, dst0, src1, dst1, cur0, cur1, es0, es1);

    int blocksG = (NN * 64 + 255) / 256;  // 12500
    gather_kernel<<<blocksG, 256, 0, stream>>>((const float2*)feat,
                                               es0, off0, deg0, es1, off1, deg1,
                                               (float2*)rst);

    int blocksN = (NN + NPB - 1) / NPB;   // 1563
    node_kernel<<<blocksN, 256, 0, stream>>>(feat, rst, WTih, WThh, b_ih, b_hh, out);
}

// Round 3
// 479.395 us; speedup vs baseline: 5.9984x; 1.1621x over previous
//
#include <hip/hip_runtime.h>
#include <hip/hip_fp16.h>
#include <cmath>

#define NN 50000
#define NE 800000
#define HIDDEN_C 128
#define NPB 32

__device__ __forceinline__ float sigmoidf_(float x) {
    return 1.0f / (1.0f + __expf(-x));
}
__device__ __forceinline__ float tanhf_(float x) {
    float t = __expf(-2.0f * fabsf(x));
    float r = (1.0f - t) / (1.0f + t);
    return copysignf(r, x);
}

// ---------------- prep: feat f32->f16, weight transpose, degree hist ----
__global__ __launch_bounds__(256) void prep_kernel(
    const float* __restrict__ feat, __half* __restrict__ feat_h,
    const float* __restrict__ Wih, const float* __restrict__ Whh,
    float* __restrict__ WTih, float* __restrict__ WThh,
    const int* __restrict__ dst0, const int* __restrict__ dst1,
    int* __restrict__ deg0, int* __restrict__ deg1) {
    int i = blockIdx.x * blockDim.x + threadIdx.x;  // 0 .. 1,599,999

    // feat conversion: 6.4M floats, 4 per thread
    {
        const float4 v = ((const float4*)feat)[i];
        __half2 lo = __floats2half2_rn(v.x, v.y);
        __half2 hi = __floats2half2_rn(v.z, v.w);
        ((__half2*)feat_h)[2 * i]     = lo;
        ((__half2*)feat_h)[2 * i + 1] = hi;
    }
    // degree histograms: first 800k threads
    if (i < NE) {
        atomicAdd(&deg0[dst0[i]], 1);
        atomicAdd(&deg1[dst1[i]], 1);
    }
    // weight transpose
    if (i < 256 * 128) {
        int g = i >> 7, k = i & 127;
        WTih[k * 256 + g] = Wih[i];
    }
    if (i < 256 * 64) {
        int g = i >> 6, k = i & 63;
        WThh[k * 256 + g] = Whh[i];
    }
}

// one block per etype (grid = 2): 1024-thread single-block exclusive scan
__global__ __launch_bounds__(1024) void scan_kernel(const int* __restrict__ deg0, int* __restrict__ off0, int* __restrict__ cur0,
                                                    const int* __restrict__ deg1, int* __restrict__ off1, int* __restrict__ cur1) {
    const int* deg = blockIdx.x == 0 ? deg0 : deg1;
    int* off = blockIdx.x == 0 ? off0 : off1;
    int* cur = blockIdx.x == 0 ? cur0 : cur1;

    __shared__ int tot[1024];
    int tid = threadIdx.x;
    const int chunk = (NN + 1023) / 1024;  // 49
    int base = tid * chunk;
    int s = 0;
    for (int i = 0; i < chunk; i++) {
        int idx = base + i;
        if (idx < NN) s += deg[idx];
    }
    tot[tid] = s;
    __syncthreads();
    for (int d = 1; d < 1024; d <<= 1) {
        int v = (tid >= d) ? tot[tid - d] : 0;
        __syncthreads();
        tot[tid] += v;
        __syncthreads();
    }
    int run = (tid > 0) ? tot[tid - 1] : 0;
    for (int i = 0; i < chunk; i++) {
        int idx = base + i;
        if (idx < NN) {
            off[idx] = run;
            cur[idx] = run;
            run += deg[idx];
        }
    }
}

__global__ void scatter_kernel(const int* __restrict__ src0, const int* __restrict__ dst0,
                               const int* __restrict__ src1, const int* __restrict__ dst1,
                               int* __restrict__ cur0, int* __restrict__ cur1,
                               int* __restrict__ es0, int* __restrict__ es1) {
    int e = blockIdx.x * blockDim.x + threadIdx.x;
    if (e < NE) {
        int p0 = atomicAdd(&cur0[dst0[e]], 1);
        es0[p0] = src0[e];
        int p1 = atomicAdd(&cur1[dst1[e]], 1);
        es1[p1] = src1[e];
    }
}

// ---------------- gather: one wave per node, half2 per lane ----------------
__global__ __launch_bounds__(256) void gather_kernel(
    const __half2* __restrict__ feat2,
    const int* __restrict__ es0, const int* __restrict__ off0, const int* __restrict__ deg0,
    const int* __restrict__ es1, const int* __restrict__ off1, const int* __restrict__ deg1,
    __half2* __restrict__ rst2) {
    int wid  = (blockIdx.x * blockDim.x + threadIdx.x) >> 6;
    int lane = threadIdx.x & 63;
    if (wid >= NN) return;

    float ax0 = 0.f, ay0 = 0.f, ax1 = 0.f, ay1 = 0.f;
    int d0 = deg0[wid], o0 = off0[wid];
    int e = 0;
    for (; e + 2 <= d0; e += 2) {
        int s0 = es0[o0 + e];
        int s1 = es0[o0 + e + 1];
        float2 v0 = __half22float2(feat2[(long)s0 * 64 + lane]);
        float2 v1 = __half22float2(feat2[(long)s1 * 64 + lane]);
        ax0 += v0.x; ay0 += v0.y;
        ax0 += v1.x; ay0 += v1.y;
    }
    if (e < d0) {
        int s0 = es0[o0 + e];
        float2 v0 = __half22float2(feat2[(long)s0 * 64 + lane]);
        ax0 += v0.x; ay0 += v0.y;
    }
    int d1 = deg1[wid], o1 = off1[wid];
    e = 0;
    for (; e + 2 <= d1; e += 2) {
        int s0 = es1[o1 + e];
        int s1 = es1[o1 + e + 1];
        float2 v0 = __half22float2(feat2[(long)s0 * 64 + lane]);
        float2 v1 = __half22float2(feat2[(long)s1 * 64 + lane]);
        ax1 += v0.x; ay1 += v0.y;
        ax1 += v1.x; ay1 += v1.y;
    }
    if (e < d1) {
        int s0 = es1[o1 + e];
        float2 v0 = __half22float2(feat2[(long)s0 * 64 + lane]);
        ax1 += v0.x; ay1 += v0.y;
    }
    float inv0 = 1.0f / fmaxf((float)d0, 1.0f);
    float inv1 = 1.0f / fmaxf((float)d1, 1.0f);
    float na = fmaxf((float)((d0 > 0) + (d1 > 0)), 1.0f);
    float rx = (ax0 * inv0 + ax1 * inv1) / na;
    float ry = (ay0 * inv0 + ay1 * inv1) / na;
    rst2[(long)wid * 64 + lane] = __floats2half2_rn(rx, ry);
}

// ---------------- node kernel: gates GEMM + LSTM epilogue --------
__global__ __launch_bounds__(256) void node_kernel(
    const float* __restrict__ feat,
    const __half* __restrict__ rst_h,
    const float* __restrict__ WTih, const float* __restrict__ WThh,
    const float* __restrict__ b_ih, const float* __restrict__ b_hh,
    float* __restrict__ out) {
    __shared__ float feat_s[NPB][HIDDEN_C];
    __shared__ float rst_s[NPB][HIDDEN_C];

    int t  = threadIdx.x;
    int nb = blockIdx.x * NPB;

    for (int idx = t; idx < NPB * HIDDEN_C; idx += 256) {
        int n = idx >> 7, k = idx & 127;
        int gn = nb + n;
        float fv = 0.0f, rv = 0.0f;
        if (gn < NN) {
            fv = feat[(long)gn * 128 + k];
            rv = __half2float(rst_h[(long)gn * 128 + k]);
        }
        feat_s[n][k] = fv;
        rst_s[n][k]  = rv;
    }
    __syncthreads();

    int lane = t & 63;
    int wv   = t >> 6;

    float bias[4];
#pragma unroll
    for (int c = 0; c < 4; c++) bias[c] = b_ih[c * 64 + lane] + b_hh[c * 64 + lane];

    float acc[8][4];
#pragma unroll
    for (int it = 0; it < 8; it++)
#pragma unroll
        for (int c = 0; c < 4; c++) acc[it][c] = bias[c];

    for (int k = 0; k < 128; k++) {
        float w0 = WTih[k * 256 + 0 * 64 + lane];
        float w1 = WTih[k * 256 + 1 * 64 + lane];
        float w2 = WTih[k * 256 + 2 * 64 + lane];
        float w3 = WTih[k * 256 + 3 * 64 + lane];
#pragma unroll
        for (int it = 0; it < 8; it++) {
            float fv = feat_s[wv + 4 * it][k];
            acc[it][0] = fmaf(fv, w0, acc[it][0]);
            acc[it][1] = fmaf(fv, w1, acc[it][1]);
            acc[it][2] = fmaf(fv, w2, acc[it][2]);
            acc[it][3] = fmaf(fv, w3, acc[it][3]);
        }
    }
    for (int k = 0; k < 64; k++) {
        float w0 = WThh[k * 256 + 0 * 64 + lane];
        float w1 = WThh[k * 256 + 1 * 64 + lane];
        float w2 = WThh[k * 256 + 2 * 64 + lane];
        float w3 = WThh[k * 256 + 3 * 64 + lane];
#pragma unroll
        for (int it = 0; it < 8; it++) {
            float gv = rst_s[wv + 4 * it][k];
            acc[it][0] = fmaf(gv, w0, acc[it][0]);
            acc[it][1] = fmaf(gv, w1, acc[it][1]);
            acc[it][2] = fmaf(gv, w2, acc[it][2]);
            acc[it][3] = fmaf(gv, w3, acc[it][3]);
        }
    }

#pragma unroll
    for (int it = 0; it < 8; it++) {
        int n  = wv + 4 * it;
        int gn = nb + n;
        if (gn >= NN) continue;
        float R  = rst_s[n][64 + lane];
        float iv = sigmoidf_(acc[it][0]);
        float fv = sigmoidf_(acc[it][1]);
        float gv = tanhf_(acc[it][2]);
        float ov = sigmoidf_(acc[it][3]);
        float c1 = fv * R + iv * gv;
        float h1 = ov * tanhf_(c1);
        out[(long)gn * 128 + lane]      = h1;
        out[(long)gn * 128 + 64 + lane] = c1;
    }
}

extern "C" void kernel_launch(void* const* d_in, const int* in_sizes, int n_in,
                              void* d_out, int out_size, void* d_ws, size_t ws_size,
                              hipStream_t stream) {
    const float* feat = (const float*)d_in[0];
    const int*   src0 = (const int*)d_in[1];
    const int*   dst0 = (const int*)d_in[2];
    const int*   src1 = (const int*)d_in[3];
    const int*   dst1 = (const int*)d_in[4];
    const float* W_ih = (const float*)d_in[5];
    const float* W_hh = (const float*)d_in[6];
    const float* b_ih = (const float*)d_in[7];
    const float* b_hh = (const float*)d_in[8];
    float* out = (float*)d_out;

    // workspace layout
    char* p = (char*)d_ws;
    int* deg0 = (int*)p;            p += NN * 4;     // zeroed
    int* deg1 = (int*)p;            p += NN * 4;     // zeroed
    int* off0 = (int*)p;            p += NN * 4;
    int* off1 = (int*)p;            p += NN * 4;
    int* cur0 = (int*)p;            p += NN * 4;
    int* cur1 = (int*)p;            p += NN * 4;
    int* es0  = (int*)p;            p += NE * 4;
    int* es1  = (int*)p;            p += NE * 4;
    __half* feat_h = (__half*)p;    p += (size_t)NN * 128 * 2;
    __half* rst_h  = (__half*)p;    p += (size_t)NN * 128 * 2;
    float* WTih = (float*)p;        p += 256 * 128 * 4;
    float* WThh = (float*)p;        p += 256 * 64 * 4;

    // zero degree histograms only
    hipMemsetAsync(deg0, 0, 2 * NN * sizeof(int), stream);

    int blocksP = (NN * 128 / 4 + 255) / 256;  // 6250
    prep_kernel<<<blocksP, 256, 0, stream>>>(feat, feat_h, W_ih, W_hh, WTih, WThh,
                                             dst0, dst1, deg0, deg1);

    scan_kernel<<<2, 1024, 0, stream>>>(deg0, off0, cur0, deg1, off1, cur1);

    int blocksE = (NE + 255) / 256;  // 3125
    scatter_kernel<<<blocksE, 256, 0, stream>>>(src0, dst0, src1, dst1, cur0, cur1, es0, es1);

    int blocksG = (NN * 64 + 255) / 256;  // 12500
    gather_kernel<<<blocksG, 256, 0, stream>>>((const __half2*)feat_h,
                                               es0, off0, deg0, es1, off1, deg1,
                                               (__half2*)rst_h);

    int blocksN = (NN + NPB - 1) / NPB;   // 1563
    node_kernel<<<blocksN, 256, 0, stream>>>(feat, rst_h, WTih, WThh, b_ih, b_hh, out);
}

// Round 4
// 371.231 us; speedup vs baseline: 7.7461x; 1.2914x over previous
//
#include <hip/hip_runtime.h>
#include <hip/hip_fp16.h>
#include <cmath>

#define NN 50000
#define NE 800000
#define HIDDEN_C 128
#define NPB 32

__device__ __forceinline__ float sigmoidf_(float x) {
    return 1.0f / (1.0f + __expf(-x));
}
__device__ __forceinline__ float tanhf_(float x) {
    float t = __expf(-2.0f * fabsf(x));
    float r = (1.0f - t) / (1.0f + t);
    return copysignf(r, x);
}

// ---------------- prep: feat f32->f16, weight transpose, degree hist ----
__global__ __launch_bounds__(256) void prep_kernel(
    const float* __restrict__ feat, __half* __restrict__ feat_h,
    const float* __restrict__ Wih, const float* __restrict__ Whh,
    float* __restrict__ WTih, float* __restrict__ WThh,
    const int* __restrict__ dst0, const int* __restrict__ dst1,
    int* __restrict__ deg0, int* __restrict__ deg1) {
    int i = blockIdx.x * blockDim.x + threadIdx.x;  // 0 .. 1,599,999

    // feat conversion: 6.4M floats, 4 per thread
    {
        const float4 v = ((const float4*)feat)[i];
        __half2 lo = __floats2half2_rn(v.x, v.y);
        __half2 hi = __floats2half2_rn(v.z, v.w);
        ((__half2*)feat_h)[2 * i]     = lo;
        ((__half2*)feat_h)[2 * i + 1] = hi;
    }
    // degree histograms: first 800k threads
    if (i < NE) {
        atomicAdd(&deg0[dst0[i]], 1);
        atomicAdd(&deg1[dst1[i]], 1);
    }
    // weight transpose
    if (i < 256 * 128) {
        int g = i >> 7, k = i & 127;
        WTih[k * 256 + g] = Wih[i];
    }
    if (i < 256 * 64) {
        int g = i >> 6, k = i & 63;
        WThh[k * 256 + g] = Whh[i];
    }
}

// ---------------- offset assignment: off[n] = atomicAdd(ctr, deg[n]) ----
// Replaces the serial scan. Ranges are disjoint+contiguous; node order of
// ranges is irrelevant to the gather.
__global__ __launch_bounds__(256) void offset_kernel(
    const int* __restrict__ deg0, int* __restrict__ off0, int* __restrict__ cur0,
    const int* __restrict__ deg1, int* __restrict__ off1, int* __restrict__ cur1,
    int* __restrict__ ctrs) {
    int i = blockIdx.x * blockDim.x + threadIdx.x;
    if (i < NN) {
        int d = deg0[i];
        int o = atomicAdd(&ctrs[0], d);
        off0[i] = o;
        cur0[i] = o;
    } else if (i < 2 * NN) {
        int n = i - NN;
        int d = deg1[n];
        int o = atomicAdd(&ctrs[1], d);
        off1[n] = o;
        cur1[n] = o;
    }
}

// ---------------- scatter: es[cur[dst]++] = src, 2 edges/thread ---------
__global__ __launch_bounds__(256) void scatter_kernel(
    const int* __restrict__ src0, const int* __restrict__ dst0,
    const int* __restrict__ src1, const int* __restrict__ dst1,
    int* __restrict__ cur0, int* __restrict__ cur1,
    int* __restrict__ es0, int* __restrict__ es1) {
    int e = (blockIdx.x * blockDim.x + threadIdx.x) * 2;
    if (e + 1 < NE) {
        int d00 = dst0[e], d01 = dst0[e + 1];
        int s00 = src0[e], s01 = src0[e + 1];
        int d10 = dst1[e], d11 = dst1[e + 1];
        int s10 = src1[e], s11 = src1[e + 1];
        int p00 = atomicAdd(&cur0[d00], 1);
        int p01 = atomicAdd(&cur0[d01], 1);
        int p10 = atomicAdd(&cur1[d10], 1);
        int p11 = atomicAdd(&cur1[d11], 1);
        es0[p00] = s00;
        es0[p01] = s01;
        es1[p10] = s10;
        es1[p11] = s11;
    } else if (e < NE) {
        int p0 = atomicAdd(&cur0[dst0[e]], 1);
        es0[p0] = src0[e];
        int p1 = atomicAdd(&cur1[dst1[e]], 1);
        es1[p1] = src1[e];
    }
}

// ---------------- gather: one wave per node, half2 per lane ----------------
__global__ __launch_bounds__(256) void gather_kernel(
    const __half2* __restrict__ feat2,
    const int* __restrict__ es0, const int* __restrict__ off0, const int* __restrict__ deg0,
    const int* __restrict__ es1, const int* __restrict__ off1, const int* __restrict__ deg1,
    __half2* __restrict__ rst2) {
    int wid  = (blockIdx.x * blockDim.x + threadIdx.x) >> 6;
    int lane = threadIdx.x & 63;
    if (wid >= NN) return;

    float ax0 = 0.f, ay0 = 0.f, ax1 = 0.f, ay1 = 0.f;
    int d0 = deg0[wid], o0 = off0[wid];
    int e = 0;
    for (; e + 2 <= d0; e += 2) {
        int s0 = es0[o0 + e];
        int s1 = es0[o0 + e + 1];
        float2 v0 = __half22float2(feat2[(long)s0 * 64 + lane]);
        float2 v1 = __half22float2(feat2[(long)s1 * 64 + lane]);
        ax0 += v0.x; ay0 += v0.y;
        ax0 += v1.x; ay0 += v1.y;
    }
    if (e < d0) {
        int s0 = es0[o0 + e];
        float2 v0 = __half22float2(feat2[(long)s0 * 64 + lane]);
        ax0 += v0.x; ay0 += v0.y;
    }
    int d1 = deg1[wid], o1 = off1[wid];
    e = 0;
    for (; e + 2 <= d1; e += 2) {
        int s0 = es1[o1 + e];
        int s1 = es1[o1 + e + 1];
        float2 v0 = __half22float2(feat2[(long)s0 * 64 + lane]);
        float2 v1 = __half22float2(feat2[(long)s1 * 64 + lane]);
        ax1 += v0.x; ay1 += v0.y;
        ax1 += v1.x; ay1 += v1.y;
    }
    if (e < d1) {
        int s0 = es1[o1 + e];
        float2 v0 = __half22float2(feat2[(long)s0 * 64 + lane]);
        ax1 += v0.x; ay1 += v0.y;
    }
    float inv0 = 1.0f / fmaxf((float)d0, 1.0f);
    float inv1 = 1.0f / fmaxf((float)d1, 1.0f);
    float na = fmaxf((float)((d0 > 0) + (d1 > 0)), 1.0f);
    float rx = (ax0 * inv0 + ax1 * inv1) / na;
    float ry = (ay0 * inv0 + ay1 * inv1) / na;
    rst2[(long)wid * 64 + lane] = __floats2half2_rn(rx, ry);
}

// ---------------- node kernel: gates GEMM + LSTM epilogue --------
__global__ __launch_bounds__(256) void node_kernel(
    const float* __restrict__ feat,
    const __half* __restrict__ rst_h,
    const float* __restrict__ WTih, const float* __restrict__ WThh,
    const float* __restrict__ b_ih, const float* __restrict__ b_hh,
    float* __restrict__ out) {
    __shared__ float feat_s[NPB][HIDDEN_C];
    __shared__ float rst_s[NPB][HIDDEN_C];

    int t  = threadIdx.x;
    int nb = blockIdx.x * NPB;

    for (int idx = t; idx < NPB * HIDDEN_C; idx += 256) {
        int n = idx >> 7, k = idx & 127;
        int gn = nb + n;
        float fv = 0.0f, rv = 0.0f;
        if (gn < NN) {
            fv = feat[(long)gn * 128 + k];
            rv = __half2float(rst_h[(long)gn * 128 + k]);
        }
        feat_s[n][k] = fv;
        rst_s[n][k]  = rv;
    }
    __syncthreads();

    int lane = t & 63;
    int wv   = t >> 6;

    float bias[4];
#pragma unroll
    for (int c = 0; c < 4; c++) bias[c] = b_ih[c * 64 + lane] + b_hh[c * 64 + lane];

    float acc[8][4];
#pragma unroll
    for (int it = 0; it < 8; it++)
#pragma unroll
        for (int c = 0; c < 4; c++) acc[it][c] = bias[c];

    for (int k = 0; k < 128; k++) {
        float w0 = WTih[k * 256 + 0 * 64 + lane];
        float w1 = WTih[k * 256 + 1 * 64 + lane];
        float w2 = WTih[k * 256 + 2 * 64 + lane];
        float w3 = WTih[k * 256 + 3 * 64 + lane];
#pragma unroll
        for (int it = 0; it < 8; it++) {
            float fv = feat_s[wv + 4 * it][k];
            acc[it][0] = fmaf(fv, w0, acc[it][0]);
            acc[it][1] = fmaf(fv, w1, acc[it][1]);
            acc[it][2] = fmaf(fv, w2, acc[it][2]);
            acc[it][3] = fmaf(fv, w3, acc[it][3]);
        }
    }
    for (int k = 0; k < 64; k++) {
        float w0 = WThh[k * 256 + 0 * 64 + lane];
        float w1 = WThh[k * 256 + 1 * 64 + lane];
        float w2 = WThh[k * 256 + 2 * 64 + lane];
        float w3 = WThh[k * 256 + 3 * 64 + lane];
#pragma unroll
        for (int it = 0; it < 8; it++) {
            float gv = rst_s[wv + 4 * it][k];
            acc[it][0] = fmaf(gv, w0, acc[it][0]);
            acc[it][1] = fmaf(gv, w1, acc[it][1]);
            acc[it][2] = fmaf(gv, w2, acc[it][2]);
            acc[it][3] = fmaf(gv, w3, acc[it][3]);
        }
    }

#pragma unroll
    for (int it = 0; it < 8; it++) {
        int n  = wv + 4 * it;
        int gn = nb + n;
        if (gn >= NN) continue;
        float R  = rst_s[n][64 + lane];
        float iv = sigmoidf_(acc[it][0]);
        float fv = sigmoidf_(acc[it][1]);
        float gv = tanhf_(acc[it][2]);
        float ov = sigmoidf_(acc[it][3]);
        float c1 = fv * R + iv * gv;
        float h1 = ov * tanhf_(c1);
        out[(long)gn * 128 + lane]      = h1;
        out[(long)gn * 128 + 64 + lane] = c1;
    }
}

extern "C" void kernel_launch(void* const* d_in, const int* in_sizes, int n_in,
                              void* d_out, int out_size, void* d_ws, size_t ws_size,
                              hipStream_t stream) {
    const float* feat = (const float*)d_in[0];
    const int*   src0 = (const int*)d_in[1];
    const int*   dst0 = (const int*)d_in[2];
    const int*   src1 = (const int*)d_in[3];
    const int*   dst1 = (const int*)d_in[4];
    const float* W_ih = (const float*)d_in[5];
    const float* W_hh = (const float*)d_in[6];
    const float* b_ih = (const float*)d_in[7];
    const float* b_hh = (const float*)d_in[8];
    float* out = (float*)d_out;

    // workspace layout
    char* p = (char*)d_ws;
    int* deg0 = (int*)p;            p += NN * 4;     // zeroed
    int* deg1 = (int*)p;            p += NN * 4;     // zeroed
    int* ctrs = (int*)p;            p += 2 * 4;      // zeroed
    int* off0 = (int*)p;            p += NN * 4;
    int* off1 = (int*)p;            p += NN * 4;
    int* cur0 = (int*)p;            p += NN * 4;
    int* cur1 = (int*)p;            p += NN * 4;
    int* es0  = (int*)p;            p += NE * 4;
    int* es1  = (int*)p;            p += NE * 4;
    __half* feat_h = (__half*)p;    p += (size_t)NN * 128 * 2;
    __half* rst_h  = (__half*)p;    p += (size_t)NN * 128 * 2;
    float* WTih = (float*)p;        p += 256 * 128 * 4;
    float* WThh = (float*)p;        p += 256 * 64 * 4;

    // zero degree histograms + counters
    hipMemsetAsync(deg0, 0, (2 * NN + 2) * sizeof(int), stream);

    int blocksP = (NN * 128 / 4 + 255) / 256;  // 6250
    prep_kernel<<<blocksP, 256, 0, stream>>>(feat, feat_h, W_ih, W_hh, WTih, WThh,
                                             dst0, dst1, deg0, deg1);

    int blocksO = (2 * NN + 255) / 256;  // 391
    offset_kernel<<<blocksO, 256, 0, stream>>>(deg0, off0, cur0, deg1, off1, cur1, ctrs);

    int blocksE = (NE / 2 + 255) / 256;  // 1563
    scatter_kernel<<<blocksE, 256, 0, stream>>>(src0, dst0, src1, dst1, cur0, cur1, es0, es1);

    int blocksG = (NN * 64 + 255) / 256;  // 12500
    gather_kernel<<<blocksG, 256, 0, stream>>>((const __half2*)feat_h,
                                               es0, off0, deg0, es1, off1, deg1,
                                               (__half2*)rst_h);

    int blocksN = (NN + NPB - 1) / NPB;   // 1563
    node_kernel<<<blocksN, 256, 0, stream>>>(feat, rst_h, WTih, WThh, b_ih, b_hh, out);
}

// Round 5
// 304.351 us; speedup vs baseline: 9.4483x; 1.2197x over previous
//
#include <hip/hip_runtime.h>
#include <hip/hip_fp16.h>
#include <cmath>

#define NN 50000
#define NE 800000
#define HIDDEN_C 128
#define NPB 32
#define NBKT 98        // ceil(50000/512)
#define BKT_SHIFT 9    // 512 nodes per bucket
#define BKT_NODES 512
#define CHUNK 8192
#define NCH 98         // ceil(800000/8192)

__device__ __forceinline__ float sigmoidf_(float x) {
    return 1.0f / (1.0f + __expf(-x));
}
__device__ __forceinline__ float tanhf_(float x) {
    float t = __expf(-2.0f * fabsf(x));
    float r = (1.0f - t) / (1.0f + t);
    return copysignf(r, x);
}

// ---------------- prep: feat f32->f16, weight transpose, degree hist ----
__global__ __launch_bounds__(256) void prep_kernel(
    const float* __restrict__ feat, __half* __restrict__ feat_h,
    const float* __restrict__ Wih, const float* __restrict__ Whh,
    float* __restrict__ WTih, float* __restrict__ WThh,
    const int* __restrict__ dst0, const int* __restrict__ dst1,
    int* __restrict__ deg0, int* __restrict__ deg1) {
    int i = blockIdx.x * blockDim.x + threadIdx.x;  // 0 .. 1,599,999

    {
        const float4 v = ((const float4*)feat)[i];
        __half2 lo = __floats2half2_rn(v.x, v.y);
        __half2 hi = __floats2half2_rn(v.z, v.w);
        ((__half2*)feat_h)[2 * i]     = lo;
        ((__half2*)feat_h)[2 * i + 1] = hi;
    }
    if (i < NE) {
        atomicAdd(&deg0[dst0[i]], 1);
        atomicAdd(&deg1[dst1[i]], 1);
    }
    if (i < 256 * 128) {
        int g = i >> 7, k = i & 127;
        WTih[k * 256 + g] = Wih[i];
    }
    if (i < 256 * 64) {
        int g = i >> 6, k = i & 63;
        WThh[k * 256 + g] = Whh[i];
    }
}

// ---------------- bucket totals + range reservation (order-free) --------
// one wave per (etype, bucket): sum deg over the bucket's 512 nodes,
// atomically reserve a contiguous range in the binned/es arrays.
__global__ __launch_bounds__(64) void bucket_sum_kernel(
    const int* __restrict__ deg0, const int* __restrict__ deg1,
    int* __restrict__ boff, int* __restrict__ bcur, int* __restrict__ bcnt,
    int* __restrict__ ctrs) {
    int g   = blockIdx.x;            // 0 .. 2*NBKT-1
    int et  = g >= NBKT;
    int b   = et ? g - NBKT : g;
    int lane = threadIdx.x;
    const int* deg = et ? deg1 : deg0;
    int node0 = b * BKT_NODES;
    int s = 0;
#pragma unroll
    for (int j = 0; j < 8; j++) {
        int idx = node0 + lane + j * 64;
        if (idx < NN) s += deg[idx];
    }
    for (int o = 32; o > 0; o >>= 1) s += __shfl_down(s, o, 64);
    if (lane == 0) {
        int o = atomicAdd(&ctrs[et], s);
        boff[g] = o;
        bcur[g] = o;
        bcnt[g] = s;
    }
}

// ---------------- phase A: bin edges into bucket-contiguous runs --------
// binned entry = (dst << 16) | src  (both < 65536)
__global__ __launch_bounds__(256) void bin_kernel(
    const int* __restrict__ src0, const int* __restrict__ dst0,
    const int* __restrict__ src1, const int* __restrict__ dst1,
    int* __restrict__ bcur,
    unsigned* __restrict__ binned0, unsigned* __restrict__ binned1) {
    __shared__ int cnt[NBKT];
    __shared__ int base[NBKT];
    __shared__ int cur[NBKT];

    int x  = blockIdx.x;             // 0 .. 2*NCH-1
    int et = x >= NCH;
    int c  = et ? x - NCH : x;
    const int* src = et ? src1 : src0;
    const int* dst = et ? dst1 : dst0;
    unsigned* binned = et ? binned1 : binned0;

    int start = c * CHUNK;
    int n = min(CHUNK, NE - start);
    int tid = threadIdx.x;

    if (tid < NBKT) { cnt[tid] = 0; cur[tid] = 0; }
    __syncthreads();
    for (int i = tid; i < n; i += 256) {
        int b = dst[start + i] >> BKT_SHIFT;
        atomicAdd(&cnt[b], 1);
    }
    __syncthreads();
    if (tid < NBKT && cnt[tid] > 0)
        base[tid] = atomicAdd(&bcur[et * NBKT + tid], cnt[tid]);
    __syncthreads();
    for (int i = tid; i < n; i += 256) {
        int d = dst[start + i];
        int b = d >> BKT_SHIFT;
        int r = atomicAdd(&cur[b], 1);
        binned[base[b] + r] = ((unsigned)d << 16) | (unsigned)src[start + i];
    }
}

// ---------------- phase B: per-bucket CSR finalize + es scatter ---------
// one block per (etype, bucket). All es writes land in the bucket's
// contiguous ~bcnt*2B region -> single-XCD, L2-resident, no write amp.
__global__ __launch_bounds__(256) void bucket_scatter_kernel(
    const unsigned* __restrict__ binned0, const unsigned* __restrict__ binned1,
    const int* __restrict__ boff, const int* __restrict__ bcnt,
    int* __restrict__ off0, int* __restrict__ off1,
    unsigned short* __restrict__ es0, unsigned short* __restrict__ es1) {
    __shared__ int lcnt[BKT_NODES];
    __shared__ int lbase[BKT_NODES];

    int g  = blockIdx.x;             // 0 .. 2*NBKT-1
    int et = g >= NBKT;
    int b  = et ? g - NBKT : g;
    const unsigned* binned = et ? binned1 : binned0;
    int* off = et ? off1 : off0;
    unsigned short* es = et ? es1 : es0;

    int bo = boff[g];
    int bn = bcnt[g];
    int node0 = b * BKT_NODES;
    int tid = threadIdx.x;

    lcnt[tid] = 0;
    lcnt[tid + 256] = 0;
    __syncthreads();
    // pass 1: per-node counts
    for (int i = tid; i < bn; i += 256) {
        unsigned u = binned[bo + i];
        int d = (int)(u >> 16) - node0;
        atomicAdd(&lcnt[d], 1);
    }
    __syncthreads();
    int o0 = lcnt[tid], o1 = lcnt[tid + 256];   // originals
    // inclusive Hillis-Steele scan over 512 entries (2 per thread)
    for (int d = 1; d < BKT_NODES; d <<= 1) {
        int v0 = (tid >= d) ? lcnt[tid - d] : 0;
        int v1 = (tid + 256 >= d) ? lcnt[tid + 256 - d] : 0;
        __syncthreads();
        lcnt[tid] += v0;
        lcnt[tid + 256] += v1;
        __syncthreads();
    }
    int e0 = lcnt[tid] - o0;          // exclusive
    int e1 = lcnt[tid + 256] - o1;
    lbase[tid] = e0;
    lbase[tid + 256] = e1;
    int gn0 = node0 + tid, gn1 = node0 + tid + 256;
    if (gn0 < NN) off[gn0] = bo + e0;
    if (gn1 < NN) off[gn1] = bo + e1;
    __syncthreads();
    // pass 2: scatter src into es within the bucket range
    for (int i = tid; i < bn; i += 256) {
        unsigned u = binned[bo + i];
        int d = (int)(u >> 16) - node0;
        int r = atomicAdd(&lbase[d], 1);
        es[bo + r] = (unsigned short)(u & 0xffffu);
    }
}

// ---------------- gather: one wave per node, half2 per lane -------------
__global__ __launch_bounds__(256) void gather_kernel(
    const __half2* __restrict__ feat2,
    const unsigned short* __restrict__ es0, const int* __restrict__ off0, const int* __restrict__ deg0,
    const unsigned short* __restrict__ es1, const int* __restrict__ off1, const int* __restrict__ deg1,
    __half2* __restrict__ rst2) {
    int wid  = (blockIdx.x * blockDim.x + threadIdx.x) >> 6;
    int lane = threadIdx.x & 63;
    if (wid >= NN) return;

    float ax0 = 0.f, ay0 = 0.f, ax1 = 0.f, ay1 = 0.f;
    int d0 = deg0[wid], o0 = off0[wid];
    int e = 0;
    for (; e + 2 <= d0; e += 2) {
        int s0 = es0[o0 + e];
        int s1 = es0[o0 + e + 1];
        float2 v0 = __half22float2(feat2[(long)s0 * 64 + lane]);
        float2 v1 = __half22float2(feat2[(long)s1 * 64 + lane]);
        ax0 += v0.x; ay0 += v0.y;
        ax0 += v1.x; ay0 += v1.y;
    }
    if (e < d0) {
        int s0 = es0[o0 + e];
        float2 v0 = __half22float2(feat2[(long)s0 * 64 + lane]);
        ax0 += v0.x; ay0 += v0.y;
    }
    int d1 = deg1[wid], o1 = off1[wid];
    e = 0;
    for (; e + 2 <= d1; e += 2) {
        int s0 = es1[o1 + e];
        int s1 = es1[o1 + e + 1];
        float2 v0 = __half22float2(feat2[(long)s0 * 64 + lane]);
        float2 v1 = __half22float2(feat2[(long)s1 * 64 + lane]);
        ax1 += v0.x; ay1 += v0.y;
        ax1 += v1.x; ay1 += v1.y;
    }
    if (e < d1) {
        int s0 = es1[o1 + e];
        float2 v0 = __half22float2(feat2[(long)s0 * 64 + lane]);
        ax1 += v0.x; ay1 += v0.y;
    }
    float inv0 = 1.0f / fmaxf((float)d0, 1.0f);
    float inv1 = 1.0f / fmaxf((float)d1, 1.0f);
    float na = fmaxf((float)((d0 > 0) + (d1 > 0)), 1.0f);
    float rx = (ax0 * inv0 + ax1 * inv1) / na;
    float ry = (ay0 * inv0 + ay1 * inv1) / na;
    rst2[(long)wid * 64 + lane] = __floats2half2_rn(rx, ry);
}

// ---------------- node kernel: gates GEMM + LSTM epilogue ---------------
__global__ __launch_bounds__(256) void node_kernel(
    const __half2* __restrict__ feat2h,
    const __half2* __restrict__ rst2h,
    const float* __restrict__ WTih, const float* __restrict__ WThh,
    const float* __restrict__ b_ih, const float* __restrict__ b_hh,
    float* __restrict__ out) {
    __shared__ float feat_s[NPB][HIDDEN_C];
    __shared__ float rst_s[NPB][HIDDEN_C];

    int t  = threadIdx.x;
    int nb = blockIdx.x * NPB;

    for (int idx = t; idx < NPB * 64; idx += 256) {
        int n = idx >> 6, k2 = idx & 63;
        int gn = nb + n;
        float2 fv = make_float2(0.f, 0.f), rv = make_float2(0.f, 0.f);
        if (gn < NN) {
            fv = __half22float2(feat2h[(long)gn * 64 + k2]);
            rv = __half22float2(rst2h[(long)gn * 64 + k2]);
        }
        feat_s[n][2 * k2]     = fv.x;
        feat_s[n][2 * k2 + 1] = fv.y;
        rst_s[n][2 * k2]      = rv.x;
        rst_s[n][2 * k2 + 1]  = rv.y;
    }
    __syncthreads();

    int lane = t & 63;
    int wv   = t >> 6;

    float bias[4];
#pragma unroll
    for (int c = 0; c < 4; c++) bias[c] = b_ih[c * 64 + lane] + b_hh[c * 64 + lane];

    float acc[8][4];
#pragma unroll
    for (int it = 0; it < 8; it++)
#pragma unroll
        for (int c = 0; c < 4; c++) acc[it][c] = bias[c];

    for (int k = 0; k < 128; k++) {
        float w0 = WTih[k * 256 + 0 * 64 + lane];
        float w1 = WTih[k * 256 + 1 * 64 + lane];
        float w2 = WTih[k * 256 + 2 * 64 + lane];
        float w3 = WTih[k * 256 + 3 * 64 + lane];
#pragma unroll
        for (int it = 0; it < 8; it++) {
            float fv = feat_s[wv + 4 * it][k];
            acc[it][0] = fmaf(fv, w0, acc[it][0]);
            acc[it][1] = fmaf(fv, w1, acc[it][1]);
            acc[it][2] = fmaf(fv, w2, acc[it][2]);
            acc[it][3] = fmaf(fv, w3, acc[it][3]);
        }
    }
    for (int k = 0; k < 64; k++) {
        float w0 = WThh[k * 256 + 0 * 64 + lane];
        float w1 = WThh[k * 256 + 1 * 64 + lane];
        float w2 = WThh[k * 256 + 2 * 64 + lane];
        float w3 = WThh[k * 256 + 3 * 64 + lane];
#pragma unroll
        for (int it = 0; it < 8; it++) {
            float gv = rst_s[wv + 4 * it][k];
            acc[it][0] = fmaf(gv, w0, acc[it][0]);
            acc[it][1] = fmaf(gv, w1, acc[it][1]);
            acc[it][2] = fmaf(gv, w2, acc[it][2]);
            acc[it][3] = fmaf(gv, w3, acc[it][3]);
        }
    }

#pragma unroll
    for (int it = 0; it < 8; it++) {
        int n  = wv + 4 * it;
        int gn = nb + n;
        if (gn >= NN) continue;
        float R  = rst_s[n][64 + lane];
        float iv = sigmoidf_(acc[it][0]);
        float fv = sigmoidf_(acc[it][1]);
        float gv = tanhf_(acc[it][2]);
        float ov = sigmoidf_(acc[it][3]);
        float c1 = fv * R + iv * gv;
        float h1 = ov * tanhf_(c1);
        out[(long)gn * 128 + lane]      = h1;
        out[(long)gn * 128 + 64 + lane] = c1;
    }
}

extern "C" void kernel_launch(void* const* d_in, const int* in_sizes, int n_in,
                              void* d_out, int out_size, void* d_ws, size_t ws_size,
                              hipStream_t stream) {
    const float* feat = (const float*)d_in[0];
    const int*   src0 = (const int*)d_in[1];
    const int*   dst0 = (const int*)d_in[2];
    const int*   src1 = (const int*)d_in[3];
    const int*   dst1 = (const int*)d_in[4];
    const float* W_ih = (const float*)d_in[5];
    const float* W_hh = (const float*)d_in[6];
    const float* b_ih = (const float*)d_in[7];
    const float* b_hh = (const float*)d_in[8];
    float* out = (float*)d_out;

    // workspace layout
    char* p = (char*)d_ws;
    int* deg0 = (int*)p;            p += NN * 4;         // zeroed
    int* deg1 = (int*)p;            p += NN * 4;         // zeroed
    int* ctrs = (int*)p;            p += 4 * 4;          // zeroed (2 used)
    int* boff = (int*)p;            p += 2 * NBKT * 4;
    int* bcur = (int*)p;            p += 2 * NBKT * 4;
    int* bcnt = (int*)p;            p += 2 * NBKT * 4;
    int* off0 = (int*)p;            p += NN * 4;
    int* off1 = (int*)p;            p += NN * 4;
    unsigned* binned0 = (unsigned*)p; p += (size_t)NE * 4;
    unsigned* binned1 = (unsigned*)p; p += (size_t)NE * 4;
    unsigned short* es0 = (unsigned short*)p; p += (size_t)NE * 2;
    unsigned short* es1 = (unsigned short*)p; p += (size_t)NE * 2;
    __half* feat_h = (__half*)p;    p += (size_t)NN * 128 * 2;
    __half* rst_h  = (__half*)p;    p += (size_t)NN * 128 * 2;
    float* WTih = (float*)p;        p += 256 * 128 * 4;
    float* WThh = (float*)p;        p += 256 * 64 * 4;

    // zero degree histograms + counters (contiguous at ws start)
    hipMemsetAsync(deg0, 0, (2 * NN + 4) * sizeof(int), stream);

    int blocksP = (NN * 128 / 4 + 255) / 256;  // 6250
    prep_kernel<<<blocksP, 256, 0, stream>>>(feat, feat_h, W_ih, W_hh, WTih, WThh,
                                             dst0, dst1, deg0, deg1);

    bucket_sum_kernel<<<2 * NBKT, 64, 0, stream>>>(deg0, deg1, boff, bcur, bcnt, ctrs);

    bin_kernel<<<2 * NCH, 256, 0, stream>>>(src0, dst0, src1, dst1, bcur, binned0, binned1);

    bucket_scatter_kernel<<<2 * NBKT, 256, 0, stream>>>(binned0, binned1, boff, bcnt,
                                                        off0, off1, es0, es1);

    int blocksG = (NN * 64 + 255) / 256;  // 12500
    gather_kernel<<<blocksG, 256, 0, stream>>>((const __half2*)feat_h,
                                               es0, off0, deg0, es1, off1, deg1,
                                               (__half2*)rst_h);

    int blocksN = (NN + NPB - 1) / NPB;   // 1563
    node_kernel<<<blocksN, 256, 0, stream>>>((const __half2*)feat_h, (const __half2*)rst_h,
                                             WTih, WThh, b_ih, b_hh, out);
}